// Round 1
// baseline (3533.237 us; speedup 1.0000x reference)
//
// Persistent cooperative LSTM kernel for MI355X (gfx950) — round 9.
//  - R3/R5-proven schedule kept VERBATIM (barriers, buffers, epilogues,
//    mm_pipe staging discipline, final pass).
//  - NEW vs round 8: reader side of the cross-block h/relu exchange is now
//    CACHED. mm_pipe uses plain global_load_dwordx4 (no sc0 sc1), and every
//    gbar ends with an agent-scope acquire fence (buffer_inv: invalidates
//    L1 + per-XCD L2). Writers stay write-through sc0 sc1 + vmcnt-drain
//    release (unchanged). Net: each phase's 32 MB of Infinity-Cache reads
//    (256 blocks x 128 KB, redundant) becomes ~1 MB of IF fills + L2 hits
//    for the other 31 blocks on each XCD; load latency ~850 -> ~200 cyc.
//  - 256 blocks x 256 threads, 1 block/CU, 4 waves = K-quarters. Weights in
//    VGPRs (160 regs); ~320 live < 512 cap at 1 wave/SIMD -> no spill.
#include <hip/hip_runtime.h>

typedef __attribute__((ext_vector_type(8))) short short8;
typedef __attribute__((ext_vector_type(4))) int int4_;
typedef __attribute__((ext_vector_type(4))) float float4_;

#define AGENT __HIP_MEMORY_SCOPE_AGENT

__device__ __forceinline__ unsigned short f2bf(float f) {
    unsigned u = __builtin_bit_cast(unsigned, f);
    u = (u + 0x7FFFu + ((u >> 16) & 1u)) >> 16;
    return (unsigned short)u;
}
__device__ __forceinline__ float bf2f(unsigned short h) {
    unsigned u = ((unsigned)h) << 16;
    return __builtin_bit_cast(float, u);
}
__device__ __forceinline__ float sigm(float x) { return 1.0f / (1.0f + __expf(-x)); }
__device__ __forceinline__ float tanhf_(float x) {
    x = fminf(fmaxf(x, -15.0f), 15.0f);
    float e = __expf(2.0f * x);
    return (e - 1.0f) / (e + 1.0f);
}

// coherent 8B store (write-through to coherence point)
__device__ __forceinline__ void st8_coh(unsigned short* p, unsigned long long v) {
    asm volatile("global_store_dwordx2 %0, %1, off sc0 sc1" :: "v"(p), "v"(v) : "memory");
}

// ---- grid barrier (R3-proven): release = vmcnt drain of the write-through
// stores; acquire = agent acquire fence (buffer_inv) so subsequent PLAIN
// loads refill L1/L2 from the coherence point. ----
__device__ __forceinline__ void gbar(unsigned* bar, unsigned target, int grpId) {
    asm volatile("s_waitcnt vmcnt(0)" ::: "memory");
    __syncthreads();
    if (threadIdx.x == 0) {
        unsigned old = __hip_atomic_fetch_add(bar + 256 + grpId * 16, 1u, __ATOMIC_RELAXED, AGENT);
        if ((old & 15u) == 15u) {
            unsigned old2 = __hip_atomic_fetch_add(bar + 512, 1u, __ATOMIC_RELAXED, AGENT);
            if ((old2 & 15u) == 15u) {
#pragma unroll
                for (int g = 0; g < 16; g++)
                    __hip_atomic_store(bar + g * 16, target, __ATOMIC_RELAXED, AGENT);
            }
        }
        while (__hip_atomic_load(bar + grpId * 16, __ATOMIC_RELAXED, AGENT) < target)
            __builtin_amdgcn_s_sleep(2);
    }
    __syncthreads();
    // Acquire: invalidate L1 + per-XCD L2 so cached reads below see the
    // freshly-published h/relu buffers. One inv per phase; fills are then
    // shared by all 32 blocks on the XCD.
    __builtin_amdgcn_fence(__ATOMIC_ACQUIRE, "agent");
}

__device__ __forceinline__ void zero4(float4_ (&a)[4]) {
    float4_ z;
    z[0] = 0.f; z[1] = 0.f; z[2] = 0.f; z[3] = 0.f;
#pragma unroll
    for (int i = 0; i < 4; i++) a[i] = z;
}

// ---- pipelined staging (R5 discipline, now CACHED loads) ----
#define LD_COH(dst, base, OFF) \
    asm volatile("global_load_dwordx4 %0, %1, off offset:" #OFF \
                 : "=v"(dst) : "v"(base))

#define ISSUE8(F, AR) \
    do { LD_COH(F[0], AR, 0);   LD_COH(F[1], AR, 64);  LD_COH(F[2], AR, 128); \
         LD_COH(F[3], AR, 192); LD_COH(F[4], AR, 256); LD_COH(F[5], AR, 320); \
         LD_COH(F[6], AR, 384); LD_COH(F[7], AR, 448); } while (0)

#define WAITV(N, F) \
    asm volatile("s_waitcnt vmcnt(" #N ")" \
                 : "+v"(F[0]), "+v"(F[1]), "+v"(F[2]), "+v"(F[3]), \
                   "+v"(F[4]), "+v"(F[5]), "+v"(F[6]), "+v"(F[7]))

#define MFMA8(F, BF, ACCI) \
    do { _Pragma("unroll") \
         for (int s_ = 0; s_ < 8; s_++) \
             ACCI = __builtin_amdgcn_mfma_f32_16x16x32_bf16( \
                 __builtin_bit_cast(short8, F[s_]), BF[s_], ACCI, 0, 0, 0); } while (0)

// A row-major [64][1024] bf16. A-frag: m = lane&15 (+16*mt), k = quad*8+j.
// Pipelined: 2-deep rotating 8-load batches, partial vmcnt(8) waits.
// Self-contained: starts at vmcnt==0, ends with WAITV(0).
__device__ __forceinline__ void mm_pipe(const unsigned short* __restrict__ A,
                                        int q, int lane,
                                        const short8 (&bf)[8], float4_ (&acc)[4]) {
    const int r0 = lane & 15;
    const int kq = (q << 8) + ((lane >> 4) << 3);
    const unsigned short* Ar0 = A + r0 * 1024 + kq;
    const unsigned short* Ar1 = Ar0 + 16 * 1024;
    const unsigned short* Ar2 = Ar0 + 32 * 1024;
    const unsigned short* Ar3 = Ar0 + 48 * 1024;
    int4_ fA[8], fB[8];
    ISSUE8(fA, Ar0);
    ISSUE8(fB, Ar1);
    WAITV(8, fA);
    MFMA8(fA, bf, acc[0]);
    ISSUE8(fA, Ar2);
    WAITV(8, fB);
    MFMA8(fB, bf, acc[1]);
    ISSUE8(fB, Ar3);
    WAITV(8, fA);
    MFMA8(fA, bf, acc[2]);
    WAITV(0, fB);
    MFMA8(fB, bf, acc[3]);
}

// C[m][n]: n = lane&15, m = quad*4+reg  -> gp[(q*64+row)*17+col]
__device__ __forceinline__ void write_parts(float* gp, int q, int lane, float4_ (&acc)[4]) {
    const int col = lane & 15;
    const int rbase = (lane >> 4) * 4;
#pragma unroll
    for (int mt = 0; mt < 4; mt++)
#pragma unroll
        for (int r = 0; r < 4; r++)
            gp[(q * 64 + mt * 16 + rbase + r) * 17 + col] = acc[mt][r];
}

__device__ __forceinline__ float gsum(const float* gp, int b, int c) {
    return gp[(0 * 64 + b) * 17 + c] + gp[(1 * 64 + b) * 17 + c] +
           gp[(2 * 64 + b) * 17 + c] + gp[(3 * 64 + b) * 17 + c];
}

__device__ __forceinline__ short8 packrow(const float* __restrict__ p) {
    short8 r;
#pragma unroll
    for (int j = 0; j < 8; j++) r[j] = (short)f2bf(p[j]);
    return r;
}

__global__ void __launch_bounds__(256, 1)
lstm_core(const float* __restrict__ x, const float* __restrict__ lastp,
          const float* __restrict__ Wih0, const float* __restrict__ Whh0,
          const float* __restrict__ bih0, const float* __restrict__ bhh0,
          const float* __restrict__ Wih1, const float* __restrict__ Whh1,
          const float* __restrict__ bih1, const float* __restrict__ bhh1,
          const float* __restrict__ W1, const float* __restrict__ b1,
          const float* __restrict__ W2, const float* __restrict__ b2,
          float* __restrict__ out, unsigned char* __restrict__ wsb)
{
    const int tid = threadIdx.x;
    const int blk = blockIdx.x;
    const int lane = tid & 63;
    const int q = tid >> 6;          // wave id = K quarter
    const int grpId = blk & 15;
    const int eb = tid >> 2;         // epilogue: batch row
    const int eu = tid & 3;          // epilogue: unit-within-block
    const int D_ = blk * 4 + eu;     // global hidden unit / fc dim

    unsigned* bar = (unsigned*)wsb;
    // row-major bf16 buffers: h[b][1024]
    unsigned short* h0buf[2] = {(unsigned short*)(wsb + 8192),
                                (unsigned short*)(wsb + 8192 + 131072)};
    unsigned short* h1buf[2] = {(unsigned short*)(wsb + 270336),
                                (unsigned short*)(wsb + 270336 + 131072)};
    unsigned short* relub = (unsigned short*)(wsb + 532480); // 32 x [64][1024]

    __shared__ float gparts[4 * 64 * 17];
    __shared__ float xlds[64 * 21];
    __shared__ float wih0l[16 * 20];
    __shared__ unsigned long long hstage_u64[64];
    unsigned short* hstage = (unsigned short*)hstage_u64;

    // ---- barrier area init (block 0) ----
    if (blk == 0 && tid == 0) {
        for (int g = 0; g < 16; g++) {
            __hip_atomic_store(bar + g * 16, 0u, __ATOMIC_RELAXED, AGENT);
            __hip_atomic_store(bar + 256 + g * 16, 0u, __ATOMIC_RELAXED, AGENT);
        }
        __hip_atomic_store(bar + 512, 0u, __ATOMIC_RELAXED, AGENT);
        __hip_atomic_store(bar + 544, 0x1357BDFu, __ATOMIC_RELEASE, AGENT);
    }

    // ---- per-lane B-fragment preload (bf16, RNE) ----
    const int n_ = lane & 15;
    const int gq_ = n_ >> 2, uu_ = n_ & 3;
    const int growL = gq_ * 1024 + blk * 4 + uu_;   // gate row for this col
    const int kq = (q << 8) + ((lane >> 4) << 3);

    short8 whh0f[8], wih1f[8], whh1f[8], wfusedf[8], wfcf[8];
#pragma unroll
    for (int s = 0; s < 8; s++) {
        const int k = kq + s * 32;
        whh0f[s] = packrow(Whh0 + growL * 1024 + k);
        wih1f[s] = packrow(Wih1 + growL * 1024 + k);
        whh1f[s] = packrow(Whh1 + growL * 1024 + k);
        { // Wfused[row][k] = sum_m Wih0[row][m] * W2[m][k]
            float a8[8] = {0.f, 0.f, 0.f, 0.f, 0.f, 0.f, 0.f, 0.f};
            for (int m = 0; m < 20; m++) {
                float wv = Wih0[growL * 20 + m];
                const float* w2p = W2 + m * 1024 + k;
#pragma unroll
                for (int j = 0; j < 8; j++) a8[j] += wv * w2p[j];
            }
            short8 r;
#pragma unroll
            for (int j = 0; j < 8; j++) r[j] = (short)f2bf(a8[j]);
            wfusedf[s] = r;
        }
        { // fc B: cols 0-3 = W1h rows, cols 4-7 = Wskip rows, 8-15 = 0
            short8 r;
            if (n_ < 4) {
                r = packrow(W1 + (blk * 4 + n_) * 1040 + k);
            } else if (n_ < 8) {
                const int D = blk * 4 + (n_ - 4);
                float a8[8] = {0.f, 0.f, 0.f, 0.f, 0.f, 0.f, 0.f, 0.f};
                for (int g2 = 0; g2 < 16; g2++) {
                    const int m = 5 * (g2 >> 2) + (g2 & 3);
                    float wv = W1[D * 1040 + 1024 + g2] * 0.01f;
                    const float* w2p = W2 + m * 1024 + k;
#pragma unroll
                    for (int j = 0; j < 8; j++) a8[j] += wv * w2p[j];
                }
#pragma unroll
                for (int j = 0; j < 8; j++) r[j] = (short)f2bf(a8[j]);
            } else {
#pragma unroll
                for (int j = 0; j < 8; j++) r[j] = 0;
            }
            wfcf[s] = r;
        }
    }

    // ---- per-thread constants (epilogue mapping: eb = tid>>2, eu = tid&3) ----
    float bias0g[4], bias1g[4], cgv[4];
#pragma unroll
    for (int g = 0; g < 4; g++) {
        const int row = g * 1024 + D_;
        bias0g[g] = bih0[row] + bhh0[row];
        bias1g[g] = bih1[row] + bhh1[row];
        float s = 0.f;
        for (int m = 0; m < 20; m++) s += Wih0[row * 20 + m] * b2[m];
        cgv[g] = s;
    }
    const float fcb = b1[D_];
    float cbv = 0.f, ustate = 0.f;
    for (int g2 = 0; g2 < 16; g2++) {
        const float w1v = W1[D_ * 1040 + 1024 + g2];
        cbv += b2[5 * (g2 >> 2) + (g2 & 3)] * w1v * 0.01f;
        ustate += lastp[eb * 16 + g2] * w1v;   // u(0) = lp0 @ W1lp^T
    }
    float c0v = 0.f, c1v = 0.f;

    if (tid < 16) { // Wih0 rows for x-path (fp32, exact)
        const int row = (tid >> 2) * 1024 + blk * 4 + (tid & 3);
        for (int m = 0; m < 20; m++) wih0l[tid * 20 + m] = Wih0[row * 20 + m];
    }
    // zero initial h state (parity 1 is "t = -1"); coherent stores
    if (tid < 64) {
        st8_coh(h0buf[1] + tid * 1024 + blk * 4, 0ull);
        st8_coh(h1buf[1] + tid * 1024 + blk * 4, 0ull);
    }

    if (tid == 0) {
        while (__hip_atomic_load(bar + 544, __ATOMIC_RELAXED, AGENT) != 0x1357BDFu)
            __builtin_amdgcn_s_sleep(2);
    }
    unsigned tgt = 1;
    gbar(bar, tgt++, grpId);

    // ---- phase lambdas (R3-verbatim epilogues) ----
    auto stage_and_store = [&](unsigned short* dst, unsigned short val) {
        hstage[tid] = val;           // hstage[eb*4+eu] == hstage[tid]
        __syncthreads();
        if (tid < 64)
            st8_coh(dst + tid * 1024 + blk * 4, hstage_u64[tid]);
    };

    auto do_l0 = [&](const unsigned short* h0prev, unsigned short* h0dst,
                     const unsigned short* reluprev, int xt) {
        if (xt >= 0) {  // stage x BEFORE the pipelined mm (vmcnt accounting)
            for (int i = tid; i < 1280; i += 256) {
                const int bb = i / 20, mm = i - bb * 20;
                xlds[bb * 21 + mm] = x[bb * 1280 + xt * 20 + mm];
            }
            asm volatile("s_waitcnt vmcnt(0)" ::: "memory");
        }
        float4_ acc[4];
        zero4(acc);
        mm_pipe(h0prev, q, lane, whh0f, acc);
        if (reluprev) mm_pipe(reluprev, q, lane, wfusedf, acc);
        write_parts(gparts, q, lane, acc);
        __syncthreads();
        float gv[4];
#pragma unroll
        for (int g = 0; g < 4; g++) gv[g] = gsum(gparts, eb, g * 4 + eu) + bias0g[g];
        if (xt >= 0) {
#pragma unroll
            for (int g = 0; g < 4; g++) {
                float s = 0.f;
                const float* wr = &wih0l[(g * 4 + eu) * 20];
                const float* xr = &xlds[eb * 21];
                for (int m = 0; m < 20; m++) s += xr[m] * wr[m];
                gv[g] += s;
            }
        } else {
#pragma unroll
            for (int g = 0; g < 4; g++) gv[g] += cgv[g];
        }
        const float iv = sigm(gv[0]), fv = sigm(gv[1]);
        const float gt = tanhf_(gv[2]), ov = sigm(gv[3]);
        c0v = fv * c0v + iv * gt;
        stage_and_store(h0dst, f2bf(ov * tanhf_(c0v)));
    };

    auto do_l1 = [&](const unsigned short* h0cur, const unsigned short* h1prev,
                     unsigned short* h1dst) {
        float4_ acc[4];
        zero4(acc);
        mm_pipe(h0cur, q, lane, wih1f, acc);
        mm_pipe(h1prev, q, lane, whh1f, acc);
        write_parts(gparts, q, lane, acc);
        __syncthreads();
        float gv[4];
#pragma unroll
        for (int g = 0; g < 4; g++) gv[g] = gsum(gparts, eb, g * 4 + eu) + bias1g[g];
        const float iv = sigm(gv[0]), fv = sigm(gv[1]);
        const float gt = tanhf_(gv[2]), ov = sigm(gv[3]);
        c1v = fv * c1v + iv * gt;
        stage_and_store(h1dst, f2bf(ov * tanhf_(c1v)));
    };

    auto do_fc = [&](int t, const unsigned short* h1cur, const unsigned short* reluprev) {
        float4_ acc1[4], acc2[4];
        zero4(acc1);
        zero4(acc2);
        mm_pipe(h1cur, q, lane, wfcf, acc1);              // cols 0-3 valid: W1h@h1
        if (reluprev) mm_pipe(reluprev, q, lane, wfcf, acc2); // cols 4-7: Wskip@relu
        {
            const int col = lane & 15;
            const int rbase = (lane >> 4) * 4;
            if (col < 8) {
#pragma unroll
                for (int mt = 0; mt < 4; mt++)
#pragma unroll
                    for (int r = 0; r < 4; r++) {
                        const float v = (col < 4) ? acc1[mt][r] : acc2[mt][r];
                        gparts[(q * 64 + mt * 16 + rbase + r) * 17 + col] = v;
                    }
            }
        }
        __syncthreads();
        const float s1 = gsum(gparts, eb, eu);
        if (t > 0) ustate += gsum(gparts, eb, 4 + eu) + cbv;
        const float rv = fmaxf(s1 + ustate + fcb, 0.f);
        stage_and_store(relub + t * 65536, f2bf(rv));
    };

    // ---- encoder: 64 steps x {L0, barrier, L1} (post-L1 barrier elided) ----
    for (int t = 0; t < 64; t++) {
        do_l0(h0buf[(t + 1) & 1], h0buf[t & 1], nullptr, t);
        gbar(bar, tgt++, grpId);
        do_l1(h0buf[t & 1], h1buf[(t + 1) & 1], h1buf[t & 1]);
    }
    // ---- decoder: 32 steps x {L0, b, L1, b, FC, b} ----
    for (int t = 0; t < 32; t++) {
        const unsigned short* rp = (t > 0) ? (relub + (t - 1) * 65536) : nullptr;
        do_l0(h0buf[(t + 1) & 1], h0buf[t & 1], rp, (t == 0) ? 63 : -1);
        gbar(bar, tgt++, grpId);
        do_l1(h0buf[t & 1], h1buf[(t + 1) & 1], h1buf[t & 1]);
        gbar(bar, tgt++, grpId);
        do_fc(t, h1buf[t & 1], rp);
        gbar(bar, tgt++, grpId);
    }

    // ---- final: pred[t] = relu[t] @ W2^T + b2 -> out[b][t][m] ----
    {
        const int pj = tid >> 5;   // 8 (t,b) pairs per block
        const int m = tid & 31;
        if (m < 20) {
            const int pidx = blk * 8 + pj;
            const int tt = pidx >> 6, bb = pidx & 63;
            const unsigned short* rr = relub + tt * 65536 + bb * 1024;
            const float* w = W2 + m * 1024;
            float acc = 0.f;
            for (int k2 = 0; k2 < 1024; k2 += 8) {
                short8 r8 = *(const short8*)(rr + k2);
#pragma unroll
                for (int j = 0; j < 8; j++)
                    acc += bf2f((unsigned short)r8[j]) * w[k2 + j];
            }
            out[bb * 640 + tt * 20 + m] = acc + b2[m];
        }
    }
}

extern "C" void kernel_launch(void* const* d_in, const int* in_sizes, int n_in,
                              void* d_out, int out_size, void* d_ws, size_t ws_size,
                              hipStream_t stream) {
    (void)in_sizes; (void)n_in; (void)out_size; (void)ws_size;
    const float* x     = (const float*)d_in[0];
    const float* lastp = (const float*)d_in[1];
    const float* Wih0  = (const float*)d_in[2];
    const float* Whh0  = (const float*)d_in[3];
    const float* bih0  = (const float*)d_in[4];
    const float* bhh0  = (const float*)d_in[5];
    const float* Wih1  = (const float*)d_in[6];
    const float* Whh1  = (const float*)d_in[7];
    const float* bih1  = (const float*)d_in[8];
    const float* bhh1  = (const float*)d_in[9];
    const float* W1    = (const float*)d_in[10];
    const float* b1    = (const float*)d_in[11];
    const float* W2    = (const float*)d_in[12];
    const float* b2    = (const float*)d_in[13];
    float* out = (float*)d_out;
    unsigned char* ws = (unsigned char*)d_ws;

    void* args[] = {&x, &lastp, &Wih0, &Whh0, &bih0, &bhh0, &Wih1, &Whh1,
                    &bih1, &bhh1, &W1, &b1, &W2, &b2, &out, &ws};
    hipError_t err = hipLaunchCooperativeKernel((const void*)lstm_core,
                                                dim3(256), dim3(256), args, 0, stream);
    if (err != hipSuccess) {
        hipLaunchKernelGGL(lstm_core, dim3(256), dim3(256), 0, stream,
                           x, lastp, Wih0, Whh0, bih0, bhh0, Wih1, Whh1,
                           bih1, bhh1, W1, b1, W2, b2, out, ws);
    }
}

// Round 2
// 2443.876 us; speedup vs baseline: 1.4458x; 1.4458x over previous
//
// Persistent cooperative LSTM kernel for MI355X (gfx950) — round 10.
//  - R3/R5-proven schedule kept VERBATIM (barriers WITHOUT any fence,
//    epilogues, mm_pipe staging discipline, final pass).
//  - NEW vs round 8: ROTATING h-buffers + plain cached reads.
//      * Every step g publishes h0/h1 into a FRESH 128 KB region (97 regions
//        each for h0/h1, g = -1..95). A never-before-touched address cannot
//        have a stale line in any L1/L2, so plain (cached) loads are
//        coherent by construction — no invalidates needed (R9's fence was
//        the regression: per-block L2 invalidates destroyed cross-block
//        sharing). Writers stay R3-proven sc0 sc1 write-through + vmcnt
//        drain before the barrier.
//      * Per XCD, the first block's read fills L2 once; the other 31 blocks
//        hit L2. Phase read traffic at the coherence point drops ~32x.
//      * relub already used this publish-once/read-cached pattern in R8's
//        final pass (proven).
//  - Needs ws_size >= 8 KB + 226*128 KB (~28.3 MB). If the workspace is
//    smaller, the launcher falls back to lstm_core<false> == R8-exact
//    (coherent sc0 sc1 reads, parity double-buffer).
//  - 256 blocks x 256 threads, 1 block/CU, 4 waves = K-quarters. Weights in
//    VGPRs (160 regs).
#include <hip/hip_runtime.h>

typedef __attribute__((ext_vector_type(8))) short short8;
typedef __attribute__((ext_vector_type(4))) int int4_;
typedef __attribute__((ext_vector_type(4))) float float4_;

#define AGENT __HIP_MEMORY_SCOPE_AGENT

__device__ __forceinline__ unsigned short f2bf(float f) {
    unsigned u = __builtin_bit_cast(unsigned, f);
    u = (u + 0x7FFFu + ((u >> 16) & 1u)) >> 16;
    return (unsigned short)u;
}
__device__ __forceinline__ float bf2f(unsigned short h) {
    unsigned u = ((unsigned)h) << 16;
    return __builtin_bit_cast(float, u);
}
__device__ __forceinline__ float sigm(float x) { return 1.0f / (1.0f + __expf(-x)); }
__device__ __forceinline__ float tanhf_(float x) {
    x = fminf(fmaxf(x, -15.0f), 15.0f);
    float e = __expf(2.0f * x);
    return (e - 1.0f) / (e + 1.0f);
}

// coherent 8B store (write-through to coherence point)
__device__ __forceinline__ void st8_coh(unsigned short* p, unsigned long long v) {
    asm volatile("global_store_dwordx2 %0, %1, off sc0 sc1" :: "v"(p), "v"(v) : "memory");
}

// ---- grid barrier (R3-verbatim): no fences; release = vmcnt drain of the
// write-through stores; acquire for rotating buffers = freshness (first
// touch per address per dispatch), acquire for fallback = sc0 sc1 loads ----
__device__ __forceinline__ void gbar(unsigned* bar, unsigned target, int grpId) {
    asm volatile("s_waitcnt vmcnt(0)" ::: "memory");
    __syncthreads();
    if (threadIdx.x == 0) {
        unsigned old = __hip_atomic_fetch_add(bar + 256 + grpId * 16, 1u, __ATOMIC_RELAXED, AGENT);
        if ((old & 15u) == 15u) {
            unsigned old2 = __hip_atomic_fetch_add(bar + 512, 1u, __ATOMIC_RELAXED, AGENT);
            if ((old2 & 15u) == 15u) {
#pragma unroll
                for (int g = 0; g < 16; g++)
                    __hip_atomic_store(bar + g * 16, target, __ATOMIC_RELAXED, AGENT);
            }
        }
        while (__hip_atomic_load(bar + grpId * 16, __ATOMIC_RELAXED, AGENT) < target)
            __builtin_amdgcn_s_sleep(2);
    }
    __syncthreads();
}

__device__ __forceinline__ void zero4(float4_ (&a)[4]) {
    float4_ z;
    z[0] = 0.f; z[1] = 0.f; z[2] = 0.f; z[3] = 0.f;
#pragma unroll
    for (int i = 0; i < 4; i++) a[i] = z;
}

// ---- pipelined staging (R5 discipline). LD_C = coherent, LD_P = cached ----
#define LD_C(dst, base, OFF) \
    asm volatile("global_load_dwordx4 %0, %1, off offset:" #OFF " sc0 sc1" \
                 : "=v"(dst) : "v"(base))
#define LD_P(dst, base, OFF) \
    asm volatile("global_load_dwordx4 %0, %1, off offset:" #OFF \
                 : "=v"(dst) : "v"(base))

#define ISSUE8(F, AR, LD) \
    do { LD(F[0], AR, 0);   LD(F[1], AR, 64);  LD(F[2], AR, 128); \
         LD(F[3], AR, 192); LD(F[4], AR, 256); LD(F[5], AR, 320); \
         LD(F[6], AR, 384); LD(F[7], AR, 448); } while (0)

#define WAITV(N, F) \
    asm volatile("s_waitcnt vmcnt(" #N ")" \
                 : "+v"(F[0]), "+v"(F[1]), "+v"(F[2]), "+v"(F[3]), \
                   "+v"(F[4]), "+v"(F[5]), "+v"(F[6]), "+v"(F[7]))

#define MFMA8(F, BF, ACCI) \
    do { _Pragma("unroll") \
         for (int s_ = 0; s_ < 8; s_++) \
             ACCI = __builtin_amdgcn_mfma_f32_16x16x32_bf16( \
                 __builtin_bit_cast(short8, F[s_]), BF[s_], ACCI, 0, 0, 0); } while (0)

// A row-major [64][1024] bf16. A-frag: m = lane&15 (+16*mt), k = quad*8+j.
// Pipelined: 2-deep rotating 8-load batches, partial vmcnt(8) waits.
// Self-contained: starts at vmcnt==0, ends with WAITV(0).
template<bool COH>
__device__ __forceinline__ void mm_pipe(const unsigned short* __restrict__ A,
                                        int q, int lane,
                                        const short8 (&bf)[8], float4_ (&acc)[4]) {
    const int r0 = lane & 15;
    const int kq = (q << 8) + ((lane >> 4) << 3);
    const unsigned short* Ar0 = A + r0 * 1024 + kq;
    const unsigned short* Ar1 = Ar0 + 16 * 1024;
    const unsigned short* Ar2 = Ar0 + 32 * 1024;
    const unsigned short* Ar3 = Ar0 + 48 * 1024;
    int4_ fA[8], fB[8];
    if constexpr (COH) {
        ISSUE8(fA, Ar0, LD_C);
        ISSUE8(fB, Ar1, LD_C);
        WAITV(8, fA);
        MFMA8(fA, bf, acc[0]);
        ISSUE8(fA, Ar2, LD_C);
        WAITV(8, fB);
        MFMA8(fB, bf, acc[1]);
        ISSUE8(fB, Ar3, LD_C);
        WAITV(8, fA);
        MFMA8(fA, bf, acc[2]);
        WAITV(0, fB);
        MFMA8(fB, bf, acc[3]);
    } else {
        ISSUE8(fA, Ar0, LD_P);
        ISSUE8(fB, Ar1, LD_P);
        WAITV(8, fA);
        MFMA8(fA, bf, acc[0]);
        ISSUE8(fA, Ar2, LD_P);
        WAITV(8, fB);
        MFMA8(fB, bf, acc[1]);
        ISSUE8(fB, Ar3, LD_P);
        WAITV(8, fA);
        MFMA8(fA, bf, acc[2]);
        WAITV(0, fB);
        MFMA8(fB, bf, acc[3]);
    }
}

// C[m][n]: n = lane&15, m = quad*4+reg  -> gp[(q*64+row)*17+col]
__device__ __forceinline__ void write_parts(float* gp, int q, int lane, float4_ (&acc)[4]) {
    const int col = lane & 15;
    const int rbase = (lane >> 4) * 4;
#pragma unroll
    for (int mt = 0; mt < 4; mt++)
#pragma unroll
        for (int r = 0; r < 4; r++)
            gp[(q * 64 + mt * 16 + rbase + r) * 17 + col] = acc[mt][r];
}

__device__ __forceinline__ float gsum(const float* gp, int b, int c) {
    return gp[(0 * 64 + b) * 17 + c] + gp[(1 * 64 + b) * 17 + c] +
           gp[(2 * 64 + b) * 17 + c] + gp[(3 * 64 + b) * 17 + c];
}

__device__ __forceinline__ short8 packrow(const float* __restrict__ p) {
    short8 r;
#pragma unroll
    for (int j = 0; j < 8; j++) r[j] = (short)f2bf(p[j]);
    return r;
}

// ROT=true : rotating fresh regions (plain cached mm reads).
// ROT=false: R8-exact (parity double-buffer, coherent sc0 sc1 mm reads).
template<bool ROT>
__global__ void __launch_bounds__(256, 1)
lstm_core(const float* __restrict__ x, const float* __restrict__ lastp,
          const float* __restrict__ Wih0, const float* __restrict__ Whh0,
          const float* __restrict__ bih0, const float* __restrict__ bhh0,
          const float* __restrict__ Wih1, const float* __restrict__ Whh1,
          const float* __restrict__ bih1, const float* __restrict__ bhh1,
          const float* __restrict__ W1, const float* __restrict__ b1,
          const float* __restrict__ W2, const float* __restrict__ b2,
          float* __restrict__ out, unsigned char* __restrict__ wsb)
{
    const int tid = threadIdx.x;
    const int blk = blockIdx.x;
    const int lane = tid & 63;
    const int q = tid >> 6;          // wave id = K quarter
    const int grpId = blk & 15;
    const int eb = tid >> 2;         // epilogue: batch row
    const int eu = tid & 3;          // epilogue: unit-within-block
    const int D_ = blk * 4 + eu;     // global hidden unit / fc dim

    unsigned* bar = (unsigned*)wsb;
    // h region bases. ROT: 97 regions each (g=-1..95), 131072 B apiece.
    unsigned short* h0base = (unsigned short*)(wsb + 8192);
    unsigned short* h1base = (unsigned short*)(wsb + (ROT ? 12722176u : 270336u));
    unsigned short* relub  = (unsigned short*)(wsb + (ROT ? 25436160u : 532480u));

    auto h0p = [&](int g) -> unsigned short* {
        return h0base + (size_t)(ROT ? (g + 1) : (g & 1)) * 65536;
    };
    auto h1p = [&](int g) -> unsigned short* {
        return h1base + (size_t)(ROT ? (g + 1) : (g & 1)) * 65536;
    };

    __shared__ float gparts[4 * 64 * 17];
    __shared__ float xlds[64 * 21];
    __shared__ float wih0l[16 * 20];
    __shared__ unsigned long long hstage_u64[64];
    unsigned short* hstage = (unsigned short*)hstage_u64;

    // ---- barrier area init (block 0) ----
    if (blk == 0 && tid == 0) {
        for (int g = 0; g < 16; g++) {
            __hip_atomic_store(bar + g * 16, 0u, __ATOMIC_RELAXED, AGENT);
            __hip_atomic_store(bar + 256 + g * 16, 0u, __ATOMIC_RELAXED, AGENT);
        }
        __hip_atomic_store(bar + 512, 0u, __ATOMIC_RELAXED, AGENT);
        __hip_atomic_store(bar + 544, 0x1357BDFu, __ATOMIC_RELEASE, AGENT);
    }

    // ---- per-lane B-fragment preload (bf16, RNE) ----
    const int n_ = lane & 15;
    const int gq_ = n_ >> 2, uu_ = n_ & 3;
    const int growL = gq_ * 1024 + blk * 4 + uu_;   // gate row for this col
    const int kq = (q << 8) + ((lane >> 4) << 3);

    short8 whh0f[8], wih1f[8], whh1f[8], wfusedf[8], wfcf[8];
#pragma unroll
    for (int s = 0; s < 8; s++) {
        const int k = kq + s * 32;
        whh0f[s] = packrow(Whh0 + growL * 1024 + k);
        wih1f[s] = packrow(Wih1 + growL * 1024 + k);
        whh1f[s] = packrow(Whh1 + growL * 1024 + k);
        { // Wfused[row][k] = sum_m Wih0[row][m] * W2[m][k]
            float a8[8] = {0.f, 0.f, 0.f, 0.f, 0.f, 0.f, 0.f, 0.f};
            for (int m = 0; m < 20; m++) {
                float wv = Wih0[growL * 20 + m];
                const float* w2p = W2 + m * 1024 + k;
#pragma unroll
                for (int j = 0; j < 8; j++) a8[j] += wv * w2p[j];
            }
            short8 r;
#pragma unroll
            for (int j = 0; j < 8; j++) r[j] = (short)f2bf(a8[j]);
            wfusedf[s] = r;
        }
        { // fc B: cols 0-3 = W1h rows, cols 4-7 = Wskip rows, 8-15 = 0
            short8 r;
            if (n_ < 4) {
                r = packrow(W1 + (blk * 4 + n_) * 1040 + k);
            } else if (n_ < 8) {
                const int D = blk * 4 + (n_ - 4);
                float a8[8] = {0.f, 0.f, 0.f, 0.f, 0.f, 0.f, 0.f, 0.f};
                for (int g2 = 0; g2 < 16; g2++) {
                    const int m = 5 * (g2 >> 2) + (g2 & 3);
                    float wv = W1[D * 1040 + 1024 + g2] * 0.01f;
                    const float* w2p = W2 + m * 1024 + k;
#pragma unroll
                    for (int j = 0; j < 8; j++) a8[j] += wv * w2p[j];
                }
#pragma unroll
                for (int j = 0; j < 8; j++) r[j] = (short)f2bf(a8[j]);
            } else {
#pragma unroll
                for (int j = 0; j < 8; j++) r[j] = 0;
            }
            wfcf[s] = r;
        }
    }

    // ---- per-thread constants (epilogue mapping: eb = tid>>2, eu = tid&3) ----
    float bias0g[4], bias1g[4], cgv[4];
#pragma unroll
    for (int g = 0; g < 4; g++) {
        const int row = g * 1024 + D_;
        bias0g[g] = bih0[row] + bhh0[row];
        bias1g[g] = bih1[row] + bhh1[row];
        float s = 0.f;
        for (int m = 0; m < 20; m++) s += Wih0[row * 20 + m] * b2[m];
        cgv[g] = s;
    }
    const float fcb = b1[D_];
    float cbv = 0.f, ustate = 0.f;
    for (int g2 = 0; g2 < 16; g2++) {
        const float w1v = W1[D_ * 1040 + 1024 + g2];
        cbv += b2[5 * (g2 >> 2) + (g2 & 3)] * w1v * 0.01f;
        ustate += lastp[eb * 16 + g2] * w1v;   // u(0) = lp0 @ W1lp^T
    }
    float c0v = 0.f, c1v = 0.f;

    if (tid < 16) { // Wih0 rows for x-path (fp32, exact)
        const int row = (tid >> 2) * 1024 + blk * 4 + (tid & 3);
        for (int m = 0; m < 20; m++) wih0l[tid * 20 + m] = Wih0[row * 20 + m];
    }
    // zero initial h state (g = -1); coherent stores
    if (tid < 64) {
        st8_coh(h0p(-1) + tid * 1024 + blk * 4, 0ull);
        st8_coh(h1p(-1) + tid * 1024 + blk * 4, 0ull);
    }

    if (tid == 0) {
        while (__hip_atomic_load(bar + 544, __ATOMIC_RELAXED, AGENT) != 0x1357BDFu)
            __builtin_amdgcn_s_sleep(2);
    }
    unsigned tgt = 1;
    gbar(bar, tgt++, grpId);

    // ---- phase lambdas (R3-verbatim epilogues) ----
    auto stage_and_store = [&](unsigned short* dst, unsigned short val) {
        hstage[tid] = val;           // hstage[eb*4+eu] == hstage[tid]
        __syncthreads();
        if (tid < 64)
            st8_coh(dst + tid * 1024 + blk * 4, hstage_u64[tid]);
    };

    auto do_l0 = [&](const unsigned short* h0prev, unsigned short* h0dst,
                     const unsigned short* reluprev, int xt) {
        if (xt >= 0) {  // stage x BEFORE the pipelined mm (vmcnt accounting)
            for (int i = tid; i < 1280; i += 256) {
                const int bb = i / 20, mm = i - bb * 20;
                xlds[bb * 21 + mm] = x[bb * 1280 + xt * 20 + mm];
            }
            asm volatile("s_waitcnt vmcnt(0)" ::: "memory");
        }
        float4_ acc[4];
        zero4(acc);
        mm_pipe<!ROT>(h0prev, q, lane, whh0f, acc);
        if (reluprev) mm_pipe<!ROT>(reluprev, q, lane, wfusedf, acc);
        write_parts(gparts, q, lane, acc);
        __syncthreads();
        float gv[4];
#pragma unroll
        for (int g = 0; g < 4; g++) gv[g] = gsum(gparts, eb, g * 4 + eu) + bias0g[g];
        if (xt >= 0) {
#pragma unroll
            for (int g = 0; g < 4; g++) {
                float s = 0.f;
                const float* wr = &wih0l[(g * 4 + eu) * 20];
                const float* xr = &xlds[eb * 21];
                for (int m = 0; m < 20; m++) s += xr[m] * wr[m];
                gv[g] += s;
            }
        } else {
#pragma unroll
            for (int g = 0; g < 4; g++) gv[g] += cgv[g];
        }
        const float iv = sigm(gv[0]), fv = sigm(gv[1]);
        const float gt = tanhf_(gv[2]), ov = sigm(gv[3]);
        c0v = fv * c0v + iv * gt;
        stage_and_store(h0dst, f2bf(ov * tanhf_(c0v)));
    };

    auto do_l1 = [&](const unsigned short* h0cur, const unsigned short* h1prev,
                     unsigned short* h1dst) {
        float4_ acc[4];
        zero4(acc);
        mm_pipe<!ROT>(h0cur, q, lane, wih1f, acc);
        mm_pipe<!ROT>(h1prev, q, lane, whh1f, acc);
        write_parts(gparts, q, lane, acc);
        __syncthreads();
        float gv[4];
#pragma unroll
        for (int g = 0; g < 4; g++) gv[g] = gsum(gparts, eb, g * 4 + eu) + bias1g[g];
        const float iv = sigm(gv[0]), fv = sigm(gv[1]);
        const float gt = tanhf_(gv[2]), ov = sigm(gv[3]);
        c1v = fv * c1v + iv * gt;
        stage_and_store(h1dst, f2bf(ov * tanhf_(c1v)));
    };

    auto do_fc = [&](int t, const unsigned short* h1cur, const unsigned short* reluprev) {
        float4_ acc1[4], acc2[4];
        zero4(acc1);
        zero4(acc2);
        mm_pipe<!ROT>(h1cur, q, lane, wfcf, acc1);              // cols 0-3: W1h@h1
        if (reluprev) mm_pipe<!ROT>(reluprev, q, lane, wfcf, acc2); // cols 4-7
        {
            const int col = lane & 15;
            const int rbase = (lane >> 4) * 4;
            if (col < 8) {
#pragma unroll
                for (int mt = 0; mt < 4; mt++)
#pragma unroll
                    for (int r = 0; r < 4; r++) {
                        const float v = (col < 4) ? acc1[mt][r] : acc2[mt][r];
                        gparts[(q * 64 + mt * 16 + rbase + r) * 17 + col] = v;
                    }
            }
        }
        __syncthreads();
        const float s1 = gsum(gparts, eb, eu);
        if (t > 0) ustate += gsum(gparts, eb, 4 + eu) + cbv;
        const float rv = fmaxf(s1 + ustate + fcb, 0.f);
        stage_and_store(relub + t * 65536, f2bf(rv));
    };

    // ---- encoder: 64 steps x {L0, barrier, L1} (post-L1 barrier elided) ----
    for (int g = 0; g < 64; g++) {
        do_l0(h0p(g - 1), h0p(g), nullptr, g);
        gbar(bar, tgt++, grpId);
        do_l1(h0p(g), h1p(g - 1), h1p(g));
    }
    // ---- decoder: 32 steps x {L0, b, L1, b, FC, b} ----
    for (int t = 0; t < 32; t++) {
        const int g = 64 + t;
        const unsigned short* rp = (t > 0) ? (relub + (t - 1) * 65536) : nullptr;
        do_l0(h0p(g - 1), h0p(g), rp, (t == 0) ? 63 : -1);
        gbar(bar, tgt++, grpId);
        do_l1(h0p(g), h1p(g - 1), h1p(g));
        gbar(bar, tgt++, grpId);
        do_fc(t, h1p(g), rp);
        gbar(bar, tgt++, grpId);
    }

    // ---- final: pred[t] = relu[t] @ W2^T + b2 -> out[b][t][m] ----
    {
        const int pj = tid >> 5;   // 8 (t,b) pairs per block
        const int m = tid & 31;
        if (m < 20) {
            const int pidx = blk * 8 + pj;
            const int tt = pidx >> 6, bb = pidx & 63;
            const unsigned short* rr = relub + tt * 65536 + bb * 1024;
            const float* w = W2 + m * 1024;
            float acc = 0.f;
            for (int k2 = 0; k2 < 1024; k2 += 8) {
                short8 r8 = *(const short8*)(rr + k2);
#pragma unroll
                for (int j = 0; j < 8; j++)
                    acc += bf2f((unsigned short)r8[j]) * w[k2 + j];
            }
            out[bb * 640 + tt * 20 + m] = acc + b2[m];
        }
    }
}

extern "C" void kernel_launch(void* const* d_in, const int* in_sizes, int n_in,
                              void* d_out, int out_size, void* d_ws, size_t ws_size,
                              hipStream_t stream) {
    (void)in_sizes; (void)n_in; (void)out_size;
    const float* x     = (const float*)d_in[0];
    const float* lastp = (const float*)d_in[1];
    const float* Wih0  = (const float*)d_in[2];
    const float* Whh0  = (const float*)d_in[3];
    const float* bih0  = (const float*)d_in[4];
    const float* bhh0  = (const float*)d_in[5];
    const float* Wih1  = (const float*)d_in[6];
    const float* Whh1  = (const float*)d_in[7];
    const float* bih1  = (const float*)d_in[8];
    const float* bhh1  = (const float*)d_in[9];
    const float* W1    = (const float*)d_in[10];
    const float* b1    = (const float*)d_in[11];
    const float* W2    = (const float*)d_in[12];
    const float* b2    = (const float*)d_in[13];
    float* out = (float*)d_out;
    unsigned char* ws = (unsigned char*)d_ws;

    void* args[] = {&x, &lastp, &Wih0, &Whh0, &bih0, &bhh0, &Wih1, &Whh1,
                    &bih1, &bhh1, &W1, &b1, &W2, &b2, &out, &ws};

    // rotation needs: 8 KB bar + (97+97+32) * 128 KB regions
    const size_t need = 8192u + (size_t)226 * 131072u;
    if (ws_size >= need) {
        hipError_t err = hipLaunchCooperativeKernel((const void*)lstm_core<true>,
                                                    dim3(256), dim3(256), args, 0, stream);
        if (err != hipSuccess) {
            hipLaunchKernelGGL(lstm_core<true>, dim3(256), dim3(256), 0, stream,
                               x, lastp, Wih0, Whh0, bih0, bhh0, Wih1, Whh1,
                               bih1, bhh1, W1, b1, W2, b2, out, ws);
        }
    } else {
        hipError_t err = hipLaunchCooperativeKernel((const void*)lstm_core<false>,
                                                    dim3(256), dim3(256), args, 0, stream);
        if (err != hipSuccess) {
            hipLaunchKernelGGL(lstm_core<false>, dim3(256), dim3(256), 0, stream,
                               x, lastp, Wih0, Whh0, bih0, bhh0, Wih1, Whh1,
                               bih1, bhh1, W1, b1, W2, b2, out, ws);
        }
    }
}

// Round 3
// 1740.580 us; speedup vs baseline: 2.0299x; 1.4041x over previous
//
// Persistent cooperative LSTM kernel for MI355X (gfx950) — round 11.
//  - R3/R5-proven schedule kept VERBATIM (barriers, epilogues, mm staging
//    discipline, final pass structure). R10 rotation machinery kept.
//  - NEW vs round 10: CHUNKED h/relu exchange layout to kill partial-line
//    write amplification. R10 counters: WRITE_SIZE 470 MB / FETCH_SIZE
//    436 MB vs only 28.7 MB of payload publishes => 16x RMW amplification
//    from 64x 8B stores at stride 2048B, drained by vmcnt(0) before every
//    gbar (160x on the critical path).
//      * Region = 256 chunks x 512 B; chunk c (= owning block) holds
//        [64 batches][4 units]: element (b,u) at (u>>2)*512 + b*8 + (u&3)*2.
//      * Publish: wave 0, 64 lanes x 8B CONTIGUOUS (blk*512 + tid*8) = 4
//        full 128B lines per store instruction. Amplification 16x -> 1x.
//      * mm_pipe reads: each 16B k-fragment spans 2 chunks -> 2x dwordx2
//        (bases[s=0..7] at s*4096, offsets mt*128 and mt*128+512). Same
//        lane->(m,k) mapping, same 2-deep rotating pipeline, partial
//        vmcnt(16) waits, self-contained (ends vmcnt(0)).
//      * Math bit-identical: absmax must stay 0.0009765625 (canary).
//  - 256 blocks x 256 threads, 1 block/CU, 4 waves = K-quarters. Weights in
//    VGPRs (160 regs).
#include <hip/hip_runtime.h>

typedef __attribute__((ext_vector_type(8))) short short8;
typedef __attribute__((ext_vector_type(4))) float float4_;
typedef unsigned long long u64;
typedef __attribute__((ext_vector_type(2))) unsigned long long u64x2;

#define AGENT __HIP_MEMORY_SCOPE_AGENT

__device__ __forceinline__ unsigned short f2bf(float f) {
    unsigned u = __builtin_bit_cast(unsigned, f);
    u = (u + 0x7FFFu + ((u >> 16) & 1u)) >> 16;
    return (unsigned short)u;
}
__device__ __forceinline__ float bf2f(unsigned short h) {
    unsigned u = ((unsigned)h) << 16;
    return __builtin_bit_cast(float, u);
}
__device__ __forceinline__ float sigm(float x) { return 1.0f / (1.0f + __expf(-x)); }
__device__ __forceinline__ float tanhf_(float x) {
    x = fminf(fmaxf(x, -15.0f), 15.0f);
    float e = __expf(2.0f * x);
    return (e - 1.0f) / (e + 1.0f);
}

// coherent 8B store (write-through to coherence point)
__device__ __forceinline__ void st8_coh(unsigned short* p, unsigned long long v) {
    asm volatile("global_store_dwordx2 %0, %1, off sc0 sc1" :: "v"(p), "v"(v) : "memory");
}

// ---- grid barrier (R3-verbatim): no fences; release = vmcnt drain of the
// write-through stores; acquire for rotating buffers = freshness, acquire
// for fallback = sc0 sc1 loads ----
__device__ __forceinline__ void gbar(unsigned* bar, unsigned target, int grpId) {
    asm volatile("s_waitcnt vmcnt(0)" ::: "memory");
    __syncthreads();
    if (threadIdx.x == 0) {
        unsigned old = __hip_atomic_fetch_add(bar + 256 + grpId * 16, 1u, __ATOMIC_RELAXED, AGENT);
        if ((old & 15u) == 15u) {
            unsigned old2 = __hip_atomic_fetch_add(bar + 512, 1u, __ATOMIC_RELAXED, AGENT);
            if ((old2 & 15u) == 15u) {
#pragma unroll
                for (int g = 0; g < 16; g++)
                    __hip_atomic_store(bar + g * 16, target, __ATOMIC_RELAXED, AGENT);
            }
        }
        while (__hip_atomic_load(bar + grpId * 16, __ATOMIC_RELAXED, AGENT) < target)
            __builtin_amdgcn_s_sleep(2);
    }
    __syncthreads();
}

__device__ __forceinline__ void zero4(float4_ (&a)[4]) {
    float4_ z;
    z[0] = 0.f; z[1] = 0.f; z[2] = 0.f; z[3] = 0.f;
#pragma unroll
    for (int i = 0; i < 4; i++) a[i] = z;
}

// ---- pipelined chunked staging. LD2C = coherent, LD2P = cached ----
#define LD2C(dst, base, OFF) \
    asm volatile("global_load_dwordx2 %0, %1, off offset:" #OFF " sc0 sc1" \
                 : "=v"(dst) : "v"(base))
#define LD2P(dst, base, OFF) \
    asm volatile("global_load_dwordx2 %0, %1, off offset:" #OFF \
                 : "=v"(dst) : "v"(base))

// 16 loads = one batch-tile (mt): 8 s-blocks x {lo,hi} chunk halves.
#define ISSUE16(LO, HI, LD, O0, O1) \
    do { LD(LO[0], bs0, O0); LD(LO[1], bs1, O0); LD(LO[2], bs2, O0); \
         LD(LO[3], bs3, O0); LD(LO[4], bs4, O0); LD(LO[5], bs5, O0); \
         LD(LO[6], bs6, O0); LD(LO[7], bs7, O0); \
         LD(HI[0], bs0, O1); LD(HI[1], bs1, O1); LD(HI[2], bs2, O1); \
         LD(HI[3], bs3, O1); LD(HI[4], bs4, O1); LD(HI[5], bs5, O1); \
         LD(HI[6], bs6, O1); LD(HI[7], bs7, O1); } while (0)

#define WAITV16(N, LO, HI) \
    asm volatile("s_waitcnt vmcnt(" #N ")" \
                 : "+v"(LO[0]), "+v"(LO[1]), "+v"(LO[2]), "+v"(LO[3]), \
                   "+v"(LO[4]), "+v"(LO[5]), "+v"(LO[6]), "+v"(LO[7]), \
                   "+v"(HI[0]), "+v"(HI[1]), "+v"(HI[2]), "+v"(HI[3]), \
                   "+v"(HI[4]), "+v"(HI[5]), "+v"(HI[6]), "+v"(HI[7]))

#define MFMA8C(LO, HI, BF, ACCI) \
    do { _Pragma("unroll") \
         for (int s_ = 0; s_ < 8; s_++) { \
             u64x2 t_; t_[0] = LO[s_]; t_[1] = HI[s_]; \
             ACCI = __builtin_amdgcn_mfma_f32_16x16x32_bf16( \
                 __builtin_bit_cast(short8, t_), BF[s_], ACCI, 0, 0, 0); } } while (0)

// A chunked [256 chunks][64 b][4 u] bf16. A-frag: m = lane&15 (+16*mt),
// k = q*256 + (lane>>4)*8 + s*32 + j. Chunk pair for (s): bases[s], +512.
// Pipelined: 2-deep rotating 16-load batches, partial vmcnt(16) waits.
// Self-contained: starts at vmcnt==0, ends with WAITV16(0).
template<bool COH>
__device__ __forceinline__ void mm_pipe(const unsigned short* __restrict__ A,
                                        int q, int lane,
                                        const short8 (&bf)[8], float4_ (&acc)[4]) {
    const char* bs0 = (const char*)A + q * 32768 + (lane >> 4) * 1024 + (lane & 15) * 8;
    const char* bs1 = bs0 + 4096;
    const char* bs2 = bs0 + 8192;
    const char* bs3 = bs0 + 12288;
    const char* bs4 = bs0 + 16384;
    const char* bs5 = bs0 + 20480;
    const char* bs6 = bs0 + 24576;
    const char* bs7 = bs0 + 28672;
    u64 loA[8], hiA[8], loB[8], hiB[8];
    if constexpr (COH) {
        ISSUE16(loA, hiA, LD2C, 0, 512);
        ISSUE16(loB, hiB, LD2C, 128, 640);
        WAITV16(16, loA, hiA);
        MFMA8C(loA, hiA, bf, acc[0]);
        ISSUE16(loA, hiA, LD2C, 256, 768);
        WAITV16(16, loB, hiB);
        MFMA8C(loB, hiB, bf, acc[1]);
        ISSUE16(loB, hiB, LD2C, 384, 896);
        WAITV16(16, loA, hiA);
        MFMA8C(loA, hiA, bf, acc[2]);
        WAITV16(0, loB, hiB);
        MFMA8C(loB, hiB, bf, acc[3]);
    } else {
        ISSUE16(loA, hiA, LD2P, 0, 512);
        ISSUE16(loB, hiB, LD2P, 128, 640);
        WAITV16(16, loA, hiA);
        MFMA8C(loA, hiA, bf, acc[0]);
        ISSUE16(loA, hiA, LD2P, 256, 768);
        WAITV16(16, loB, hiB);
        MFMA8C(loB, hiB, bf, acc[1]);
        ISSUE16(loB, hiB, LD2P, 384, 896);
        WAITV16(16, loA, hiA);
        MFMA8C(loA, hiA, bf, acc[2]);
        WAITV16(0, loB, hiB);
        MFMA8C(loB, hiB, bf, acc[3]);
    }
}

// C[m][n]: n = lane&15, m = quad*4+reg  -> gp[(q*64+row)*17+col]
__device__ __forceinline__ void write_parts(float* gp, int q, int lane, float4_ (&acc)[4]) {
    const int col = lane & 15;
    const int rbase = (lane >> 4) * 4;
#pragma unroll
    for (int mt = 0; mt < 4; mt++)
#pragma unroll
        for (int r = 0; r < 4; r++)
            gp[(q * 64 + mt * 16 + rbase + r) * 17 + col] = acc[mt][r];
}

__device__ __forceinline__ float gsum(const float* gp, int b, int c) {
    return gp[(0 * 64 + b) * 17 + c] + gp[(1 * 64 + b) * 17 + c] +
           gp[(2 * 64 + b) * 17 + c] + gp[(3 * 64 + b) * 17 + c];
}

__device__ __forceinline__ short8 packrow(const float* __restrict__ p) {
    short8 r;
#pragma unroll
    for (int j = 0; j < 8; j++) r[j] = (short)f2bf(p[j]);
    return r;
}

// ROT=true : rotating fresh regions (plain cached mm reads).
// ROT=false: parity double-buffer, coherent sc0 sc1 mm reads (R8 scheme).
template<bool ROT>
__global__ void __launch_bounds__(256, 1)
lstm_core(const float* __restrict__ x, const float* __restrict__ lastp,
          const float* __restrict__ Wih0, const float* __restrict__ Whh0,
          const float* __restrict__ bih0, const float* __restrict__ bhh0,
          const float* __restrict__ Wih1, const float* __restrict__ Whh1,
          const float* __restrict__ bih1, const float* __restrict__ bhh1,
          const float* __restrict__ W1, const float* __restrict__ b1,
          const float* __restrict__ W2, const float* __restrict__ b2,
          float* __restrict__ out, unsigned char* __restrict__ wsb)
{
    const int tid = threadIdx.x;
    const int blk = blockIdx.x;
    const int lane = tid & 63;
    const int q = tid >> 6;          // wave id = K quarter
    const int grpId = blk & 15;
    const int eb = tid >> 2;         // epilogue: batch row
    const int eu = tid & 3;          // epilogue: unit-within-block
    const int D_ = blk * 4 + eu;     // global hidden unit / fc dim

    unsigned* bar = (unsigned*)wsb;
    // h region bases. ROT: 97 regions each (g=-1..95), 131072 B apiece.
    unsigned short* h0base = (unsigned short*)(wsb + 8192);
    unsigned short* h1base = (unsigned short*)(wsb + (ROT ? 12722176u : 270336u));
    unsigned short* relub  = (unsigned short*)(wsb + (ROT ? 25436160u : 532480u));

    auto h0p = [&](int g) -> unsigned short* {
        return h0base + (size_t)(ROT ? (g + 1) : (g & 1)) * 65536;
    };
    auto h1p = [&](int g) -> unsigned short* {
        return h1base + (size_t)(ROT ? (g + 1) : (g & 1)) * 65536;
    };

    __shared__ float gparts[4 * 64 * 17];
    __shared__ float xlds[64 * 21];
    __shared__ float wih0l[16 * 20];
    __shared__ unsigned long long hstage_u64[64];
    unsigned short* hstage = (unsigned short*)hstage_u64;

    // ---- barrier area init (block 0) ----
    if (blk == 0 && tid == 0) {
        for (int g = 0; g < 16; g++) {
            __hip_atomic_store(bar + g * 16, 0u, __ATOMIC_RELAXED, AGENT);
            __hip_atomic_store(bar + 256 + g * 16, 0u, __ATOMIC_RELAXED, AGENT);
        }
        __hip_atomic_store(bar + 512, 0u, __ATOMIC_RELAXED, AGENT);
        __hip_atomic_store(bar + 544, 0x1357BDFu, __ATOMIC_RELEASE, AGENT);
    }

    // ---- per-lane B-fragment preload (bf16, RNE) ----
    const int n_ = lane & 15;
    const int gq_ = n_ >> 2, uu_ = n_ & 3;
    const int growL = gq_ * 1024 + blk * 4 + uu_;   // gate row for this col
    const int kq = (q << 8) + ((lane >> 4) << 3);

    short8 whh0f[8], wih1f[8], whh1f[8], wfusedf[8], wfcf[8];
#pragma unroll
    for (int s = 0; s < 8; s++) {
        const int k = kq + s * 32;
        whh0f[s] = packrow(Whh0 + growL * 1024 + k);
        wih1f[s] = packrow(Wih1 + growL * 1024 + k);
        whh1f[s] = packrow(Whh1 + growL * 1024 + k);
        { // Wfused[row][k] = sum_m Wih0[row][m] * W2[m][k]
            float a8[8] = {0.f, 0.f, 0.f, 0.f, 0.f, 0.f, 0.f, 0.f};
            for (int m = 0; m < 20; m++) {
                float wv = Wih0[growL * 20 + m];
                const float* w2p = W2 + m * 1024 + k;
#pragma unroll
                for (int j = 0; j < 8; j++) a8[j] += wv * w2p[j];
            }
            short8 r;
#pragma unroll
            for (int j = 0; j < 8; j++) r[j] = (short)f2bf(a8[j]);
            wfusedf[s] = r;
        }
        { // fc B: cols 0-3 = W1h rows, cols 4-7 = Wskip rows, 8-15 = 0
            short8 r;
            if (n_ < 4) {
                r = packrow(W1 + (blk * 4 + n_) * 1040 + k);
            } else if (n_ < 8) {
                const int D = blk * 4 + (n_ - 4);
                float a8[8] = {0.f, 0.f, 0.f, 0.f, 0.f, 0.f, 0.f, 0.f};
                for (int g2 = 0; g2 < 16; g2++) {
                    const int m = 5 * (g2 >> 2) + (g2 & 3);
                    float wv = W1[D * 1040 + 1024 + g2] * 0.01f;
                    const float* w2p = W2 + m * 1024 + k;
#pragma unroll
                    for (int j = 0; j < 8; j++) a8[j] += wv * w2p[j];
                }
#pragma unroll
                for (int j = 0; j < 8; j++) r[j] = (short)f2bf(a8[j]);
            } else {
#pragma unroll
                for (int j = 0; j < 8; j++) r[j] = 0;
            }
            wfcf[s] = r;
        }
    }

    // ---- per-thread constants (epilogue mapping: eb = tid>>2, eu = tid&3) ----
    float bias0g[4], bias1g[4], cgv[4];
#pragma unroll
    for (int g = 0; g < 4; g++) {
        const int row = g * 1024 + D_;
        bias0g[g] = bih0[row] + bhh0[row];
        bias1g[g] = bih1[row] + bhh1[row];
        float s = 0.f;
        for (int m = 0; m < 20; m++) s += Wih0[row * 20 + m] * b2[m];
        cgv[g] = s;
    }
    const float fcb = b1[D_];
    float cbv = 0.f, ustate = 0.f;
    for (int g2 = 0; g2 < 16; g2++) {
        const float w1v = W1[D_ * 1040 + 1024 + g2];
        cbv += b2[5 * (g2 >> 2) + (g2 & 3)] * w1v * 0.01f;
        ustate += lastp[eb * 16 + g2] * w1v;   // u(0) = lp0 @ W1lp^T
    }
    float c0v = 0.f, c1v = 0.f;

    if (tid < 16) { // Wih0 rows for x-path (fp32, exact)
        const int row = (tid >> 2) * 1024 + blk * 4 + (tid & 3);
        for (int m = 0; m < 20; m++) wih0l[tid * 20 + m] = Wih0[row * 20 + m];
    }
    // zero initial h state (g = -1); chunked: chunk blk, batch tid
    if (tid < 64) {
        st8_coh(h0p(-1) + blk * 256 + tid * 4, 0ull);
        st8_coh(h1p(-1) + blk * 256 + tid * 4, 0ull);
    }

    if (tid == 0) {
        while (__hip_atomic_load(bar + 544, __ATOMIC_RELAXED, AGENT) != 0x1357BDFu)
            __builtin_amdgcn_s_sleep(2);
    }
    unsigned tgt = 1;
    gbar(bar, tgt++, grpId);

    // ---- phase lambdas (R3-verbatim epilogues; chunked publish) ----
    auto stage_and_store = [&](unsigned short* dst, unsigned short val) {
        hstage[tid] = val;           // hstage[eb*4+eu] == hstage[tid]
        __syncthreads();
        if (tid < 64)                // chunk blk, batch tid: 512B contiguous
            st8_coh(dst + blk * 256 + tid * 4, hstage_u64[tid]);
    };

    auto do_l0 = [&](const unsigned short* h0prev, unsigned short* h0dst,
                     const unsigned short* reluprev, int xt) {
        if (xt >= 0) {  // stage x BEFORE the pipelined mm (vmcnt accounting)
            for (int i = tid; i < 1280; i += 256) {
                const int bb = i / 20, mm = i - bb * 20;
                xlds[bb * 21 + mm] = x[bb * 1280 + xt * 20 + mm];
            }
            asm volatile("s_waitcnt vmcnt(0)" ::: "memory");
        }
        float4_ acc[4];
        zero4(acc);
        mm_pipe<!ROT>(h0prev, q, lane, whh0f, acc);
        if (reluprev) mm_pipe<!ROT>(reluprev, q, lane, wfusedf, acc);
        write_parts(gparts, q, lane, acc);
        __syncthreads();
        float gv[4];
#pragma unroll
        for (int g = 0; g < 4; g++) gv[g] = gsum(gparts, eb, g * 4 + eu) + bias0g[g];
        if (xt >= 0) {
#pragma unroll
            for (int g = 0; g < 4; g++) {
                float s = 0.f;
                const float* wr = &wih0l[(g * 4 + eu) * 20];
                const float* xr = &xlds[eb * 21];
                for (int m = 0; m < 20; m++) s += xr[m] * wr[m];
                gv[g] += s;
            }
        } else {
#pragma unroll
            for (int g = 0; g < 4; g++) gv[g] += cgv[g];
        }
        const float iv = sigm(gv[0]), fv = sigm(gv[1]);
        const float gt = tanhf_(gv[2]), ov = sigm(gv[3]);
        c0v = fv * c0v + iv * gt;
        stage_and_store(h0dst, f2bf(ov * tanhf_(c0v)));
    };

    auto do_l1 = [&](const unsigned short* h0cur, const unsigned short* h1prev,
                     unsigned short* h1dst) {
        float4_ acc[4];
        zero4(acc);
        mm_pipe<!ROT>(h0cur, q, lane, wih1f, acc);
        mm_pipe<!ROT>(h1prev, q, lane, whh1f, acc);
        write_parts(gparts, q, lane, acc);
        __syncthreads();
        float gv[4];
#pragma unroll
        for (int g = 0; g < 4; g++) gv[g] = gsum(gparts, eb, g * 4 + eu) + bias1g[g];
        const float iv = sigm(gv[0]), fv = sigm(gv[1]);
        const float gt = tanhf_(gv[2]), ov = sigm(gv[3]);
        c1v = fv * c1v + iv * gt;
        stage_and_store(h1dst, f2bf(ov * tanhf_(c1v)));
    };

    auto do_fc = [&](int t, const unsigned short* h1cur, const unsigned short* reluprev) {
        float4_ acc1[4], acc2[4];
        zero4(acc1);
        zero4(acc2);
        mm_pipe<!ROT>(h1cur, q, lane, wfcf, acc1);              // cols 0-3: W1h@h1
        if (reluprev) mm_pipe<!ROT>(reluprev, q, lane, wfcf, acc2); // cols 4-7
        {
            const int col = lane & 15;
            const int rbase = (lane >> 4) * 4;
            if (col < 8) {
#pragma unroll
                for (int mt = 0; mt < 4; mt++)
#pragma unroll
                    for (int r = 0; r < 4; r++) {
                        const float v = (col < 4) ? acc1[mt][r] : acc2[mt][r];
                        gparts[(q * 64 + mt * 16 + rbase + r) * 17 + col] = v;
                    }
            }
        }
        __syncthreads();
        const float s1 = gsum(gparts, eb, eu);
        if (t > 0) ustate += gsum(gparts, eb, 4 + eu) + cbv;
        const float rv = fmaxf(s1 + ustate + fcb, 0.f);
        stage_and_store(relub + t * 65536, f2bf(rv));
    };

    // ---- encoder: 64 steps x {L0, barrier, L1} (post-L1 barrier elided) ----
    for (int g = 0; g < 64; g++) {
        do_l0(h0p(g - 1), h0p(g), nullptr, g);
        gbar(bar, tgt++, grpId);
        do_l1(h0p(g), h1p(g - 1), h1p(g));
    }
    // ---- decoder: 32 steps x {L0, b, L1, b, FC, b} ----
    for (int t = 0; t < 32; t++) {
        const int g = 64 + t;
        const unsigned short* rp = (t > 0) ? (relub + (t - 1) * 65536) : nullptr;
        do_l0(h0p(g - 1), h0p(g), rp, (t == 0) ? 63 : -1);
        gbar(bar, tgt++, grpId);
        do_l1(h0p(g), h1p(g - 1), h1p(g));
        gbar(bar, tgt++, grpId);
        do_fc(t, h1p(g), rp);
        gbar(bar, tgt++, grpId);
    }

    // ---- final: pred[t] = relu[t] @ W2^T + b2 -> out[b][t][m] ----
    {
        const int pj = tid >> 5;   // 8 (t,b) pairs per block
        const int m = tid & 31;
        if (m < 20) {
            const int pidx = blk * 8 + pj;
            const int tt = pidx >> 6, bb = pidx & 63;
            const unsigned short* rr = relub + tt * 65536;  // chunked region
            const float* w = W2 + m * 1024;
            float acc = 0.f;
            for (int c = 0; c < 256; c++) {
                const u64 v8 = *(const u64*)(rr + c * 256 + bb * 4);
#pragma unroll
                for (int j = 0; j < 4; j++)
                    acc += bf2f((unsigned short)(v8 >> (16 * j))) * w[c * 4 + j];
            }
            out[bb * 640 + tt * 20 + m] = acc + b2[m];
        }
    }
}

extern "C" void kernel_launch(void* const* d_in, const int* in_sizes, int n_in,
                              void* d_out, int out_size, void* d_ws, size_t ws_size,
                              hipStream_t stream) {
    (void)in_sizes; (void)n_in; (void)out_size;
    const float* x     = (const float*)d_in[0];
    const float* lastp = (const float*)d_in[1];
    const float* Wih0  = (const float*)d_in[2];
    const float* Whh0  = (const float*)d_in[3];
    const float* bih0  = (const float*)d_in[4];
    const float* bhh0  = (const float*)d_in[5];
    const float* Wih1  = (const float*)d_in[6];
    const float* Whh1  = (const float*)d_in[7];
    const float* bih1  = (const float*)d_in[8];
    const float* bhh1  = (const float*)d_in[9];
    const float* W1    = (const float*)d_in[10];
    const float* b1    = (const float*)d_in[11];
    const float* W2    = (const float*)d_in[12];
    const float* b2    = (const float*)d_in[13];
    float* out = (float*)d_out;
    unsigned char* ws = (unsigned char*)d_ws;

    void* args[] = {&x, &lastp, &Wih0, &Whh0, &bih0, &bhh0, &Wih1, &Whh1,
                    &bih1, &bhh1, &W1, &b1, &W2, &b2, &out, &ws};

    // rotation needs: 8 KB bar + (97+97+32) * 128 KB regions
    const size_t need = 8192u + (size_t)226 * 131072u;
    if (ws_size >= need) {
        hipError_t err = hipLaunchCooperativeKernel((const void*)lstm_core<true>,
                                                    dim3(256), dim3(256), args, 0, stream);
        if (err != hipSuccess) {
            hipLaunchKernelGGL(lstm_core<true>, dim3(256), dim3(256), 0, stream,
                               x, lastp, Wih0, Whh0, bih0, bhh0, Wih1, Whh1,
                               bih1, bhh1, W1, b1, W2, b2, out, ws);
        }
    } else {
        hipError_t err = hipLaunchCooperativeKernel((const void*)lstm_core<false>,
                                                    dim3(256), dim3(256), args, 0, stream);
        if (err != hipSuccess) {
            hipLaunchKernelGGL(lstm_core<false>, dim3(256), dim3(256), 0, stream,
                               x, lastp, Wih0, Whh0, bih0, bhh0, Wih1, Whh1,
                               bih1, bhh1, W1, b1, W2, b2, out, ws);
        }
    }
}